// Round 2
// baseline (228.370 us; speedup 1.0000x reference)
//
#include <hip/hip_runtime.h>
#include <hip/hip_cooperative_groups.h>
#include <math.h>

namespace cg = cooperative_groups;

#define B 4
#define L 2048
#define H 8
#define D 64
#define SK 40
#define U 40
#define JC 16          // j-chunks in fused tail (128 j per chunk)
#define JCL (L / JC)   // 128
#define CSG 32         // csum granularity: 32 sub-chunks of 64 columns

// ws layout (bytes)
#define OFF_M     0                  // B*H*L floats = 262144 B
#define OFF_TOP   262144             // B*H*U ints  = 5120 B
#define OFF_T     270336             // B*H*U*L floats (E matrix) = 10485760 B
#define OFF_PART  10756096           // JC * B*H*U*D floats = 5242880 B
#define OFF_CSUM  15998976           // B*H*U*CSG floats = 163840 B (end ~16.2 MB)

__device__ __forceinline__ float dot4(float4 a, float4 b) {
    return fmaf(a.x, b.x, fmaf(a.y, b.y, fmaf(a.z, b.z, a.w * b.w)));
}

// K1: M[b,h,q] = max_s dot(Q[bhq], K[bh,idx[q,s]]) - (1/L) * sum_s dot(...)
// FP32 ONLY (top-k ordering; fp16 noise permutes rows). 38-44 us across 3
// structural variants -> L2 gather-bandwidth ceiling. UNCHANGED.
__global__ __launch_bounds__(256) void k_msamp(const float* __restrict__ Q,
                                               const float* __restrict__ K,
                                               const int* __restrict__ idx,
                                               float* __restrict__ M) {
    int g  = blockIdx.x & 7;        // = b*2 + hh  (XCD id under %8 round-robin)
    int b  = g >> 1;
    int hh = g & 1;
    int t  = threadIdx.x;
    int wave = t >> 6;
    int lane = t & 63;
    int qp = lane >> 5;
    int hp = (lane >> 3) & 3;
    int c  = lane & 7;
    int h  = hh * 4 + hp;
    int q  = (blockIdx.x >> 3) * 8 + wave * 2 + qp;

    const float* qrow = Q + (size_t)((b * L + q) * H + h) * D + c * 8;
    float4 qa = *(const float4*)qrow;
    float4 qb = *(const float4*)(qrow + 4);

    int s1 = lane & 31;
    int v1 = idx[q * SK + s1];
    int s2 = 32 + s1; if (s2 > SK - 1) s2 = SK - 1;
    int v2 = idx[q * SK + s2];

    const float* kbase = K + (size_t)b * L * H * D + (size_t)h * D + c * 8;

    float vmax = -__builtin_inff();
    float vsum = 0.f;
#pragma unroll 8
    for (int s = 0; s < SK; ++s) {
        int kidx = (s < 32) ? __shfl(v1, qp * 32 + s, 64)
                            : __shfl(v2, qp * 32 + (s - 32), 64);
        const float* kp = kbase + (size_t)kidx * (H * D);
        float4 ka = *(const float4*)kp;
        float4 kb = *(const float4*)(kp + 4);
        float d8 = dot4(qa, ka) + dot4(qb, kb);
        d8 += __shfl_xor(d8, 1, 64);
        d8 += __shfl_xor(d8, 2, 64);
        d8 += __shfl_xor(d8, 4, 64);
        vmax = fmaxf(vmax, d8);
        vsum += d8;
    }
    if (c == 0) M[(size_t)(b * H + h) * L + q] = vmax - vsum * (1.0f / (float)L);
}

// K2: top-U per (b,h). Order: value desc, ties -> lowest index. UNCHANGED.
__global__ __launch_bounds__(256) void k_topk(const float* __restrict__ M,
                                              int* __restrict__ top) {
    __shared__ unsigned long long cand[L];
    __shared__ unsigned int bins[256];
    __shared__ unsigned int red[256];
    __shared__ int cnt2;

    int bh = blockIdx.x;
    int tid = threadIdx.x;
    const float* m = M + (size_t)bh * L;

    bins[tid] = 0;
    if (tid == 0) cnt2 = 0;

    const float4* m4 = (const float4*)(m + tid * 8);
    float4 fa = m4[0], fb = m4[1];
    float f8[8] = {fa.x, fa.y, fa.z, fa.w, fb.x, fb.y, fb.z, fb.w};
    unsigned int u8[8];
    unsigned int umin = 0xFFFFFFFFu, umax = 0u;
#pragma unroll
    for (int e = 0; e < 8; ++e) {
        unsigned int bits = __float_as_uint(f8[e]);
        unsigned int u = (bits & 0x80000000u) ? ~bits : (bits | 0x80000000u);
        u8[e] = u;
        umin = min(umin, u);
        umax = max(umax, u);
    }
    red[tid] = umin;
    __syncthreads();
    for (int s = 128; s; s >>= 1) {
        if (tid < s) red[tid] = min(red[tid], red[tid + s]);
        __syncthreads();
    }
    unsigned int kmin = red[0];
    __syncthreads();
    red[tid] = umax;
    __syncthreads();
    for (int s = 128; s; s >>= 1) {
        if (tid < s) red[tid] = max(red[tid], red[tid + s]);
        __syncthreads();
    }
    unsigned int kmax = red[0];
    __syncthreads();

    unsigned int range = kmax - kmin;
    if (range == 0u) {
        if (tid < U) top[bh * U + tid] = tid;
        return;
    }
    int hb = 31 - __clz(range);
    int shift = (hb > 7) ? (hb - 7) : 0;

#pragma unroll
    for (int e = 0; e < 8; ++e) {
        unsigned int bin = (u8[e] - kmin) >> shift;
        atomicAdd(&bins[bin], 1u);
    }
    __syncthreads();

    red[tid] = bins[tid];
    __syncthreads();
    for (int s = 1; s < 256; s <<= 1) {
        unsigned int add = (tid + s < 256) ? red[tid + s] : 0u;
        __syncthreads();
        red[tid] += add;
        __syncthreads();
    }
    int cnt = __syncthreads_count(red[tid] >= U);
    unsigned int t = (unsigned int)(cnt - 1);

#pragma unroll
    for (int e = 0; e < 8; ++e) {
        unsigned int u = u8[e];
        if (((u - kmin) >> shift) >= t) {
            int pos = atomicAdd(&cnt2, 1);
            int i = tid * 8 + e;
            cand[pos] = ((unsigned long long)u << 11) | (unsigned long long)(2047 - i);
        }
    }
    __syncthreads();
    int C = cnt2;

    for (int j = tid; j < C; j += 256) {
        unsigned long long kj = cand[j];
        int r = 0;
        for (int kk = 0; kk < C; ++kk) r += (cand[kk] > kj);
        if (r < U) top[bh * U + r] = 2047 - (int)(kj & 0x7FFull);
    }
}

// ---- Fused tail phases, written for a 256-BLOCK decomposition ----
// Round-1 post-mortem: absmax == max|ref| exactly -> out was all-zero -> the
// 512-block cooperative launch FAILED (return code unchecked; 512 required
// exactly 2 blocks/CU). Now: 256 blocks (1/CU, always co-resident), each
// phase-A/B block handles 2 sub-chunks, and a checked fallback to 3 regular
// launches if the coop launch errors.

// Phase A: E[bh,u,k] = exp(0.125*dot(Q[top[u]],K[k])), csum = per-64-col sums.
// fp32, no max-sub (|score| <~ 6 is fp32-safe; normalization in phase C).
__device__ __forceinline__ void phaseA(const float* __restrict__ Q,
                                       const float* __restrict__ K,
                                       const int* __restrict__ top,
                                       float* __restrict__ T,
                                       float* __restrict__ csum,
                                       float4* sQ4) {
    int tid = threadIdx.x, lane = tid & 63, w = tid >> 6;
    int bh = blockIdx.x >> 3;        // 32 bh
    int kc2 = blockIdx.x & 7;        // 8 super-chunks of 256 columns
    int b = bh >> 3, h = bh & (H - 1);

    for (int i = tid; i < U * 16; i += 256) {
        int u = i >> 4, c = i & 15;
        int qidx = top[bh * U + u];
        sQ4[i] = *((const float4*)(Q + (size_t)((b * L + qidx) * H + h) * D) + c);
    }
    __syncthreads();

    float* Tb = T + (size_t)bh * U * L;
    for (int sub = 0; sub < 2; ++sub) {
        int kc = kc2 * 2 + sub;
        int k0 = kc * 128 + lane;
        const float4* kr0 = (const float4*)(K + (size_t)((b * L + k0) * H + h) * D);
        const float4* kr1 = (const float4*)(K + (size_t)((b * L + k0 + 64) * H + h) * D);
        float4 kv0[16], kv1[16];
#pragma unroll
        for (int i = 0; i < 16; ++i) { kv0[i] = kr0[i]; kv1[i] = kr1[i]; }

        for (int uu = 0; uu < 10; ++uu) {
            int u = w * 10 + uu;
            float s0 = 0.f, s1 = 0.f;
#pragma unroll
            for (int i = 0; i < 16; ++i) {
                float4 q4 = sQ4[u * 16 + i];   // broadcast LDS read
                s0 += dot4(q4, kv0[i]);
                s1 += dot4(q4, kv1[i]);
            }
            float e0 = __expf(s0 * 0.125f);
            float e1 = __expf(s1 * 0.125f);
            Tb[(size_t)u * L + k0]      = e0;
            Tb[(size_t)u * L + k0 + 64] = e1;
            float c0 = e0, c1 = e1;
#pragma unroll
            for (int o = 1; o < 64; o <<= 1) {
                c0 += __shfl_xor(c0, o, 64);
                c1 += __shfl_xor(c1, o, 64);
            }
            if (lane == 0) {
                csum[((size_t)bh * U + u) * CSG + 2 * kc]     = c0;
                csum[((size_t)bh * U + u) * CSG + 2 * kc + 1] = c1;
            }
        }
    }
}

// Phase B: per 128-j chunk, in-wave suffix scan of E (+ csum tail), then
// part[jc,bh,u,d] = sum_j Tsuf[u,j]*V[b,j,h,d].
__device__ __forceinline__ void phaseB(const float* __restrict__ V,
                                       const float* __restrict__ T,
                                       const float* __restrict__ csum,
                                       float* __restrict__ part,
                                       float* sT) {
    int tid = threadIdx.x, lane = tid & 63, w = tid >> 6;
    int bh = blockIdx.x >> 3;
    int jc2 = blockIdx.x & 7;
    int b = bh >> 3, h = bh & (H - 1);
    int j2 = lane >> 4;
    int d4 = lane & 15;
    int jlane = lane & 31;

    for (int sub = 0; sub < 2; ++sub) {
        int jc = jc2 * 2 + sub;
        if (sub) __syncthreads();           // sT reuse across sub-iterations
        const float* Eg = T + (size_t)bh * U * L + jc * JCL;
        for (int r = 0; r < 10; ++r) {
            int u = w * 10 + r;
            float cv = csum[((size_t)bh * U + u) * CSG + jlane];
            float tv = (jlane > 2 * jc + 1) ? cv : 0.f;
            tv += __shfl_xor(tv, 1, 64);
            tv += __shfl_xor(tv, 2, 64);
            tv += __shfl_xor(tv, 4, 64);
            tv += __shfl_xor(tv, 8, 64);
            tv += __shfl_xor(tv, 16, 64);
            float el = Eg[(size_t)u * L + lane];
            float eh = Eg[(size_t)u * L + 64 + lane];
            float sh = eh;
#pragma unroll
            for (int s = 1; s < 64; s <<= 1) {
                float o = __shfl_down(sh, s, 64);
                sh += (lane + s < 64) ? o : 0.f;
            }
            float th = __shfl(sh, 0, 64);   // total of hi half
            float sl = el;
#pragma unroll
            for (int s = 1; s < 64; s <<= 1) {
                float o = __shfl_down(sl, s, 64);
                sl += (lane + s < 64) ? o : 0.f;
            }
            sT[u * JCL + lane]      = sl + th + tv;
            sT[u * JCL + 64 + lane] = sh + tv;
        }
        __syncthreads();

        float4 acc[10];
#pragma unroll
        for (int uu = 0; uu < 10; ++uu) acc[uu] = make_float4(0.f, 0.f, 0.f, 0.f);

        const float* Vb = V + (size_t)(b * L) * (H * D) + (size_t)h * D + d4 * 4;
#pragma unroll 4
        for (int it = 0; it < JCL / 4; ++it) {
            int j = it * 4 + j2;
            float4 v4 = *(const float4*)(Vb + (size_t)(jc * JCL + j) * (H * D));
#pragma unroll
            for (int uu = 0; uu < 10; ++uu) {
                float tj = sT[(w * 10 + uu) * JCL + j];
                acc[uu].x = fmaf(tj, v4.x, acc[uu].x);
                acc[uu].y = fmaf(tj, v4.y, acc[uu].y);
                acc[uu].z = fmaf(tj, v4.z, acc[uu].z);
                acc[uu].w = fmaf(tj, v4.w, acc[uu].w);
            }
        }

        float* po = part + ((size_t)jc * (B * H) + bh) * (U * D);
#pragma unroll
        for (int uu = 0; uu < 10; ++uu) {
            float4 a = acc[uu];
            a.x += __shfl_xor(a.x, 16, 64); a.y += __shfl_xor(a.y, 16, 64);
            a.z += __shfl_xor(a.z, 16, 64); a.w += __shfl_xor(a.w, 16, 64);
            a.x += __shfl_xor(a.x, 32, 64); a.y += __shfl_xor(a.y, 32, 64);
            a.z += __shfl_xor(a.z, 32, 64); a.w += __shfl_xor(a.w, 32, 64);
            if (j2 == 0) *(float4*)(po + (w * 10 + uu) * D + d4 * 4) = a;
        }
    }
}

// Phase C: per-bh block (32 active) sums 16 parts + softmax-normalizes.
__device__ __forceinline__ void phaseC(const float* __restrict__ part,
                                       const float* __restrict__ csum,
                                       float* __restrict__ out,
                                       float* sden) {
    int bh = blockIdx.x;
    if (bh >= B * H) return;
    int tid = threadIdx.x;
    int jlane = tid & 31;

    for (int p = 0; p < 5; ++p) {
        int u = p * 8 + (tid >> 5);
        float v = csum[((size_t)bh * U + u) * CSG + jlane];
        v += __shfl_xor(v, 1, 64);
        v += __shfl_xor(v, 2, 64);
        v += __shfl_xor(v, 4, 64);
        v += __shfl_xor(v, 8, 64);
        v += __shfl_xor(v, 16, 64);
        if (jlane == 0) sden[u] = v;
    }
    __syncthreads();

    const float* pb = part + (size_t)bh * (U * D);
    float* ob = out + (size_t)bh * (U * D);
    for (int it = 0; it < 10; ++it) {
        int rest = it * 256 + tid;
        int u = rest >> 6;
        float s = 0.f;
#pragma unroll
        for (int jc = 0; jc < JC; ++jc)
            s += pb[(size_t)jc * (B * H) * (U * D) + rest];
        ob[rest] = s / sden[u];
    }
}

// Fused cooperative tail: 256 blocks x 256 thr (1 block/CU guaranteed).
__global__ __launch_bounds__(256, 2) void k_tail(const float* __restrict__ Q,
                                                 const float* __restrict__ K,
                                                 const int* __restrict__ top,
                                                 const float* __restrict__ V,
                                                 float* __restrict__ T,
                                                 float* __restrict__ csum,
                                                 float* __restrict__ part,
                                                 float* __restrict__ out) {
    __shared__ __align__(16) char smem[U * JCL * 4];   // 20 KB, phase-aliased
    cg::grid_group grid = cg::this_grid();
    phaseA(Q, K, top, T, csum, (float4*)smem);
    grid.sync();
    phaseB(V, T, csum, part, (float*)smem);
    grid.sync();
    phaseC(part, csum, out, (float*)smem);
}

// Fallback single-phase kernels (identical math, regular launches).
__global__ __launch_bounds__(256) void k_phA(const float* __restrict__ Q,
                                             const float* __restrict__ K,
                                             const int* __restrict__ top,
                                             float* __restrict__ T,
                                             float* __restrict__ csum) {
    __shared__ __align__(16) char smem[U * 16 * 16];
    phaseA(Q, K, top, T, csum, (float4*)smem);
}
__global__ __launch_bounds__(256) void k_phB(const float* __restrict__ V,
                                             const float* __restrict__ T,
                                             const float* __restrict__ csum,
                                             float* __restrict__ part) {
    __shared__ __align__(16) char smem[U * JCL * 4];
    phaseB(V, T, csum, part, (float*)smem);
}
__global__ __launch_bounds__(256) void k_phC(const float* __restrict__ part,
                                             const float* __restrict__ csum,
                                             float* __restrict__ out) {
    __shared__ float sden[U];
    phaseC(part, csum, out, sden);
}

extern "C" void kernel_launch(void* const* d_in, const int* in_sizes, int n_in,
                              void* d_out, int out_size, void* d_ws, size_t ws_size,
                              hipStream_t stream) {
    const float* Q  = (const float*)d_in[0];
    const float* K  = (const float*)d_in[1];
    const float* V  = (const float*)d_in[2];
    const int* idx  = (const int*)d_in[3];
    float* out = (float*)d_out;

    float* M    = (float*)((char*)d_ws + OFF_M);
    int*   top  = (int*)  ((char*)d_ws + OFF_TOP);
    float* T    = (float*)((char*)d_ws + OFF_T);
    float* part = (float*)((char*)d_ws + OFF_PART);
    float* csum = (float*)((char*)d_ws + OFF_CSUM);

    k_msamp<<<(L / 8) * 8, 256, 0, stream>>>(Q, K, idx, M);
    k_topk<<<B * H, 256, 0, stream>>>(M, top);

    void* args[] = {(void*)&Q, (void*)&K, (void*)&top, (void*)&V,
                    (void*)&T, (void*)&csum, (void*)&part, (void*)&out};
    hipError_t e = hipLaunchCooperativeKernel((const void*)k_tail, dim3(256),
                                              dim3(256), args, 0, stream);
    if (e != hipSuccess) {
        // coop launch rejected (e.g. unsupported under graph capture) ->
        // 3 regular launches of the same phase functions.
        k_phA<<<256, 256, 0, stream>>>(Q, K, top, T, csum);
        k_phB<<<256, 256, 0, stream>>>(V, T, csum, part);
        k_phC<<<B * H, 256, 0, stream>>>(part, csum, out);
    }
}

// Round 3
// 212.734 us; speedup vs baseline: 1.0735x; 1.0735x over previous
//
#include <hip/hip_runtime.h>
#include <hip/hip_cooperative_groups.h>
#include <math.h>

namespace cg = cooperative_groups;

#define B 4
#define L 2048
#define H 8
#define D 64
#define SK 40
#define U 40
#define JC 16          // j-chunks in fused tail (128 j per chunk)
#define JCL (L / JC)   // 128
#define CSG 32         // csum granularity: 32 sub-chunks of 64 columns
#define NT 1024        // tail block size: 16 waves/CU (round-2 was 256 = 4 waves
                       // -> 10% occupancy, latency-bound at 337 GB/s)

// ws layout (bytes)
#define OFF_M     0                  // B*H*L floats = 262144 B
#define OFF_TOP   262144             // B*H*U ints  = 5120 B
#define OFF_T     270336             // B*H*U*L floats (E matrix) = 10485760 B
#define OFF_PART  10756096           // JC * B*H*U*D floats = 5242880 B
#define OFF_CSUM  15998976           // B*H*U*CSG floats = 163840 B (end ~16.2 MB)

__device__ __forceinline__ float dot4(float4 a, float4 b) {
    return fmaf(a.x, b.x, fmaf(a.y, b.y, fmaf(a.z, b.z, a.w * b.w)));
}

// K1: M[b,h,q] = max_s dot(Q[bhq], K[bh,idx[q,s]]) - (1/L) * sum_s dot(...)
// FP32 ONLY (top-k ordering; fp16 noise permutes rows). 38-44 us across 3
// structural variants -> L2 gather-bandwidth ceiling. UNCHANGED.
__global__ __launch_bounds__(256) void k_msamp(const float* __restrict__ Q,
                                               const float* __restrict__ K,
                                               const int* __restrict__ idx,
                                               float* __restrict__ M) {
    int g  = blockIdx.x & 7;        // = b*2 + hh  (XCD id under %8 round-robin)
    int b  = g >> 1;
    int hh = g & 1;
    int t  = threadIdx.x;
    int wave = t >> 6;
    int lane = t & 63;
    int qp = lane >> 5;
    int hp = (lane >> 3) & 3;
    int c  = lane & 7;
    int h  = hh * 4 + hp;
    int q  = (blockIdx.x >> 3) * 8 + wave * 2 + qp;

    const float* qrow = Q + (size_t)((b * L + q) * H + h) * D + c * 8;
    float4 qa = *(const float4*)qrow;
    float4 qb = *(const float4*)(qrow + 4);

    int s1 = lane & 31;
    int v1 = idx[q * SK + s1];
    int s2 = 32 + s1; if (s2 > SK - 1) s2 = SK - 1;
    int v2 = idx[q * SK + s2];

    const float* kbase = K + (size_t)b * L * H * D + (size_t)h * D + c * 8;

    float vmax = -__builtin_inff();
    float vsum = 0.f;
#pragma unroll 8
    for (int s = 0; s < SK; ++s) {
        int kidx = (s < 32) ? __shfl(v1, qp * 32 + s, 64)
                            : __shfl(v2, qp * 32 + (s - 32), 64);
        const float* kp = kbase + (size_t)kidx * (H * D);
        float4 ka = *(const float4*)kp;
        float4 kb = *(const float4*)(kp + 4);
        float d8 = dot4(qa, ka) + dot4(qb, kb);
        d8 += __shfl_xor(d8, 1, 64);
        d8 += __shfl_xor(d8, 2, 64);
        d8 += __shfl_xor(d8, 4, 64);
        vmax = fmaxf(vmax, d8);
        vsum += d8;
    }
    if (c == 0) M[(size_t)(b * H + h) * L + q] = vmax - vsum * (1.0f / (float)L);
}

// K2: top-U per (b,h). Order: value desc, ties -> lowest index. UNCHANGED.
__global__ __launch_bounds__(256) void k_topk(const float* __restrict__ M,
                                              int* __restrict__ top) {
    __shared__ unsigned long long cand[L];
    __shared__ unsigned int bins[256];
    __shared__ unsigned int red[256];
    __shared__ int cnt2;

    int bh = blockIdx.x;
    int tid = threadIdx.x;
    const float* m = M + (size_t)bh * L;

    bins[tid] = 0;
    if (tid == 0) cnt2 = 0;

    const float4* m4 = (const float4*)(m + tid * 8);
    float4 fa = m4[0], fb = m4[1];
    float f8[8] = {fa.x, fa.y, fa.z, fa.w, fb.x, fb.y, fb.z, fb.w};
    unsigned int u8[8];
    unsigned int umin = 0xFFFFFFFFu, umax = 0u;
#pragma unroll
    for (int e = 0; e < 8; ++e) {
        unsigned int bits = __float_as_uint(f8[e]);
        unsigned int u = (bits & 0x80000000u) ? ~bits : (bits | 0x80000000u);
        u8[e] = u;
        umin = min(umin, u);
        umax = max(umax, u);
    }
    red[tid] = umin;
    __syncthreads();
    for (int s = 128; s; s >>= 1) {
        if (tid < s) red[tid] = min(red[tid], red[tid + s]);
        __syncthreads();
    }
    unsigned int kmin = red[0];
    __syncthreads();
    red[tid] = umax;
    __syncthreads();
    for (int s = 128; s; s >>= 1) {
        if (tid < s) red[tid] = max(red[tid], red[tid + s]);
        __syncthreads();
    }
    unsigned int kmax = red[0];
    __syncthreads();

    unsigned int range = kmax - kmin;
    if (range == 0u) {
        if (tid < U) top[bh * U + tid] = tid;
        return;
    }
    int hb = 31 - __clz(range);
    int shift = (hb > 7) ? (hb - 7) : 0;

#pragma unroll
    for (int e = 0; e < 8; ++e) {
        unsigned int bin = (u8[e] - kmin) >> shift;
        atomicAdd(&bins[bin], 1u);
    }
    __syncthreads();

    red[tid] = bins[tid];
    __syncthreads();
    for (int s = 1; s < 256; s <<= 1) {
        unsigned int add = (tid + s < 256) ? red[tid + s] : 0u;
        __syncthreads();
        red[tid] += add;
        __syncthreads();
    }
    int cnt = __syncthreads_count(red[tid] >= U);
    unsigned int t = (unsigned int)(cnt - 1);

#pragma unroll
    for (int e = 0; e < 8; ++e) {
        unsigned int u = u8[e];
        if (((u - kmin) >> shift) >= t) {
            int pos = atomicAdd(&cnt2, 1);
            int i = tid * 8 + e;
            cand[pos] = ((unsigned long long)u << 11) | (unsigned long long)(2047 - i);
        }
    }
    __syncthreads();
    int C = cnt2;

    for (int j = tid; j < C; j += 256) {
        unsigned long long kj = cand[j];
        int r = 0;
        for (int kk = 0; kk < C; ++kk) r += (cand[kk] > kj);
        if (r < U) top[bh * U + r] = 2047 - (int)(kj & 0x7FFull);
    }
}

// ---- Fused tail phases, 1024-thread (16-wave) decomposition ----
// Round-2 post-mortem: 256-thr blocks = 1 wave/SIMD -> k_tail 128.6 us at
// 337 GB/s, VALUBusy 8%, Occupancy 10.3% -> pure latency exposure. Coop grid
// is capped near 256 blocks (512 rejected in round 1), so waves must come
// from block SIZE: 1024 thr = 4 waves/SIMD. Per-thread serial work cut 2-4x.

// Phase A: E[bh,u,k] = exp(0.125*dot(Q[top[u]],K[k])), csum = per-64-col sums.
// fp32, no max-sub (|score| <~ 6 fp32-safe; normalization in phase C).
// Decomposition: half (512 thr) = one 128-col chunk kc; thread owns ONE K
// column (16 float4 = 64 VGPR) x 10 u (ugrp = quarter of the half).
__device__ __forceinline__ void phaseA(const float* __restrict__ Q,
                                       const float* __restrict__ K,
                                       const int* __restrict__ top,
                                       float* __restrict__ T,
                                       float* __restrict__ csum,
                                       float4* sQ4) {
    int tid = threadIdx.x;
    int bh = blockIdx.x >> 3;        // 32 bh
    int kc2 = blockIdx.x & 7;        // 8 super-chunks of 256 columns
    int b = bh >> 3, h = bh & (H - 1);

    for (int i = tid; i < U * 16; i += NT) {
        int u = i >> 4, c = i & 15;
        int qidx = top[bh * U + u];
        sQ4[i] = *((const float4*)(Q + (size_t)((b * L + qidx) * H + h) * D) + c);
    }

    int half   = tid >> 9;           // 0/1 -> which 128-col chunk
    int t512   = tid & 511;
    int ugrp   = t512 >> 7;          // 0..3 -> u in [10*ugrp, 10*ugrp+10)
    int colgrp = t512 & 127;         // column within chunk
    int kc  = kc2 * 2 + half;
    int col = kc * 128 + colgrp;

    const float4* kr = (const float4*)(K + (size_t)((b * L + col) * H + h) * D);
    float4 kv[16];
#pragma unroll
    for (int i = 0; i < 16; ++i) kv[i] = kr[i];
    __syncthreads();

    float* Tb = T + (size_t)bh * U * L;
    int cs = 2 * kc + (colgrp >> 6); // 64-col sub-chunk id (wave-uniform)
#pragma unroll
    for (int uu = 0; uu < 10; ++uu) {
        int u = ugrp * 10 + uu;
        float s = 0.f;
#pragma unroll
        for (int i = 0; i < 16; ++i) s += dot4(sQ4[u * 16 + i], kv[i]);
        float e = __expf(s * 0.125f);
        Tb[(size_t)u * L + col] = e;   // wave writes 64 consecutive floats
        float c0 = e;
#pragma unroll
        for (int o = 1; o < 64; o <<= 1) c0 += __shfl_xor(c0, o, 64);
        if ((colgrp & 63) == 0) csum[((size_t)bh * U + u) * CSG + cs] = c0;
    }
}

// Phase B: per 128-j chunk (one per 512-thr half), in-wave suffix scan of E
// (+ csum tail), then part[jc,bh,u,d] = sum_j Tsuf[u,j]*V[b,j,h,d].
// 8 waves/half x 5 u each.
__device__ __forceinline__ void phaseB(const float* __restrict__ V,
                                       const float* __restrict__ T,
                                       const float* __restrict__ csum,
                                       float* __restrict__ part,
                                       float* sTbase) {
    int tid = threadIdx.x;
    int bh = blockIdx.x >> 3;
    int jc2 = blockIdx.x & 7;
    int b = bh >> 3, h = bh & (H - 1);
    int half = tid >> 9;
    int t512 = tid & 511;
    int w8   = t512 >> 6;            // wave within half: u in [5*w8, 5*w8+5)
    int lane = t512 & 63;            // == physical lane (512 % 64 == 0)
    int jc = jc2 * 2 + half;
    float* sT = sTbase + half * (U * JCL);

    int j2 = lane >> 4;
    int d4 = lane & 15;
    int jlane = lane & 31;

    const float* Eg = T + (size_t)bh * U * L + jc * JCL;
    for (int r = 0; r < 5; ++r) {
        int u = w8 * 5 + r;
        // tail = sum of csum sub-chunks beyond this 128-j chunk
        float cv = csum[((size_t)bh * U + u) * CSG + jlane];
        float tv = (jlane > 2 * jc + 1) ? cv : 0.f;
        tv += __shfl_xor(tv, 1, 64);
        tv += __shfl_xor(tv, 2, 64);
        tv += __shfl_xor(tv, 4, 64);
        tv += __shfl_xor(tv, 8, 64);
        tv += __shfl_xor(tv, 16, 64);
        float el = Eg[(size_t)u * L + lane];
        float eh = Eg[(size_t)u * L + 64 + lane];
        float sh = eh;
#pragma unroll
        for (int s = 1; s < 64; s <<= 1) {
            float o = __shfl_down(sh, s, 64);
            sh += (lane + s < 64) ? o : 0.f;
        }
        float th = __shfl(sh, 0, 64);   // total of hi half
        float sl = el;
#pragma unroll
        for (int s = 1; s < 64; s <<= 1) {
            float o = __shfl_down(sl, s, 64);
            sl += (lane + s < 64) ? o : 0.f;
        }
        sT[u * JCL + lane]      = sl + th + tv;
        sT[u * JCL + 64 + lane] = sh + tv;
    }
    __syncthreads();

    float4 acc[5];
#pragma unroll
    for (int uu = 0; uu < 5; ++uu) acc[uu] = make_float4(0.f, 0.f, 0.f, 0.f);

    const float* Vb = V + (size_t)(b * L) * (H * D) + (size_t)h * D + d4 * 4;
#pragma unroll 4
    for (int it = 0; it < JCL / 4; ++it) {
        int j = it * 4 + j2;
        float4 v4 = *(const float4*)(Vb + (size_t)(jc * JCL + j) * (H * D));
#pragma unroll
        for (int uu = 0; uu < 5; ++uu) {
            float tj = sT[(w8 * 5 + uu) * JCL + j];   // broadcast LDS read
            acc[uu].x = fmaf(tj, v4.x, acc[uu].x);
            acc[uu].y = fmaf(tj, v4.y, acc[uu].y);
            acc[uu].z = fmaf(tj, v4.z, acc[uu].z);
            acc[uu].w = fmaf(tj, v4.w, acc[uu].w);
        }
    }

    float* po = part + ((size_t)jc * (B * H) + bh) * (U * D);
#pragma unroll
    for (int uu = 0; uu < 5; ++uu) {
        float4 a = acc[uu];
        a.x += __shfl_xor(a.x, 16, 64); a.y += __shfl_xor(a.y, 16, 64);
        a.z += __shfl_xor(a.z, 16, 64); a.w += __shfl_xor(a.w, 16, 64);
        a.x += __shfl_xor(a.x, 32, 64); a.y += __shfl_xor(a.y, 32, 64);
        a.z += __shfl_xor(a.z, 32, 64); a.w += __shfl_xor(a.w, 32, 64);
        if (j2 == 0) *(float4*)(po + (w8 * 5 + uu) * D + d4 * 4) = a;
    }
}

// Phase C: per-bh block (32 active) sums 16 parts + softmax-normalizes.
__device__ __forceinline__ void phaseC(const float* __restrict__ part,
                                       const float* __restrict__ csum,
                                       float* __restrict__ out,
                                       float* sden) {
    int bh = blockIdx.x;
    if (bh >= B * H) return;
    int tid = threadIdx.x;
    int grp = tid >> 5;              // 0..31 (32-lane groups)
    int jlane = tid & 31;

    for (int u = grp; u < U; u += 32) {
        float v = csum[((size_t)bh * U + u) * CSG + jlane];
        v += __shfl_xor(v, 1, 64);
        v += __shfl_xor(v, 2, 64);
        v += __shfl_xor(v, 4, 64);
        v += __shfl_xor(v, 8, 64);
        v += __shfl_xor(v, 16, 64);
        if (jlane == 0) sden[u] = v;
    }
    __syncthreads();

    const float* pb = part + (size_t)bh * (U * D);
    float* ob = out + (size_t)bh * (U * D);
    for (int i = tid; i < U * D; i += NT) {
        int u = i >> 6;
        float s = 0.f;
#pragma unroll
        for (int jc = 0; jc < JC; ++jc)
            s += pb[(size_t)jc * (B * H) * (U * D) + i];
        ob[i] = s / sden[u];
    }
}

// Fused cooperative tail: 256 blocks x 1024 thr (16 waves/CU, 1 block/CU).
// launch_bounds(1024,4): 4 waves/EU min -> VGPR capped at 128 so the
// 16-wave block is schedulable.
__global__ __launch_bounds__(NT, 4) void k_tail(const float* __restrict__ Q,
                                                const float* __restrict__ K,
                                                const int* __restrict__ top,
                                                const float* __restrict__ V,
                                                float* __restrict__ T,
                                                float* __restrict__ csum,
                                                float* __restrict__ part,
                                                float* __restrict__ out) {
    __shared__ __align__(16) char smem[2 * U * JCL * 4];   // 40 KB, phase-aliased
    cg::grid_group grid = cg::this_grid();
    phaseA(Q, K, top, T, csum, (float4*)smem);
    grid.sync();
    phaseB(V, T, csum, part, (float*)smem);
    grid.sync();
    phaseC(part, csum, out, (float*)smem);
}

// Fallback single-phase kernels (identical math, regular launches).
__global__ __launch_bounds__(NT, 4) void k_phA(const float* __restrict__ Q,
                                               const float* __restrict__ K,
                                               const int* __restrict__ top,
                                               float* __restrict__ T,
                                               float* __restrict__ csum) {
    __shared__ __align__(16) float4 sQ4[U * 16];
    phaseA(Q, K, top, T, csum, sQ4);
}
__global__ __launch_bounds__(NT, 4) void k_phB(const float* __restrict__ V,
                                               const float* __restrict__ T,
                                               const float* __restrict__ csum,
                                               float* __restrict__ part) {
    __shared__ __align__(16) float sT[2 * U * JCL];
    phaseB(V, T, csum, part, sT);
}
__global__ __launch_bounds__(NT, 4) void k_phC(const float* __restrict__ part,
                                               const float* __restrict__ csum,
                                               float* __restrict__ out) {
    __shared__ float sden[U];
    phaseC(part, csum, out, sden);
}

extern "C" void kernel_launch(void* const* d_in, const int* in_sizes, int n_in,
                              void* d_out, int out_size, void* d_ws, size_t ws_size,
                              hipStream_t stream) {
    const float* Q  = (const float*)d_in[0];
    const float* K  = (const float*)d_in[1];
    const float* V  = (const float*)d_in[2];
    const int* idx  = (const int*)d_in[3];
    float* out = (float*)d_out;

    float* M    = (float*)((char*)d_ws + OFF_M);
    int*   top  = (int*)  ((char*)d_ws + OFF_TOP);
    float* T    = (float*)((char*)d_ws + OFF_T);
    float* part = (float*)((char*)d_ws + OFF_PART);
    float* csum = (float*)((char*)d_ws + OFF_CSUM);

    k_msamp<<<(L / 8) * 8, 256, 0, stream>>>(Q, K, idx, M);
    k_topk<<<B * H, 256, 0, stream>>>(M, top);

    void* args[] = {(void*)&Q, (void*)&K, (void*)&top, (void*)&V,
                    (void*)&T, (void*)&csum, (void*)&part, (void*)&out};
    hipError_t e = hipLaunchCooperativeKernel((const void*)k_tail, dim3(256),
                                              dim3(NT), args, 0, stream);
    if (e != hipSuccess) {
        // coop launch rejected -> 3 regular launches of the same phases.
        k_phA<<<256, NT, 0, stream>>>(Q, K, top, T, csum);
        k_phB<<<256, NT, 0, stream>>>(V, T, csum, part);
        k_phC<<<B * H, NT, 0, stream>>>(part, csum, out);
    }
}

// Round 4
// 143.988 us; speedup vs baseline: 1.5860x; 1.4774x over previous
//
#include <hip/hip_runtime.h>
#include <math.h>

#define B 4
#define L 2048
#define H 8
#define D 64
#define SK 40
#define U 40
#define JC 16          // j-chunks in tail (128 j per chunk)
#define JCL (L / JC)   // 128
#define CSG 32         // csum granularity: 32 sub-chunks of 64 columns

// ws layout (bytes)
#define OFF_M     0                  // B*H*L floats = 262144 B
#define OFF_TOP   262144             // B*H*U ints  = 5120 B
#define OFF_T     270336             // B*H*U*L floats (E matrix) = 10485760 B
#define OFF_PART  10756096           // JC * B*H*U*D floats = 5242880 B
#define OFF_CSUM  15998976           // B*H*U*CSG floats = 163840 B (end ~16.2 MB)

__device__ __forceinline__ float dot4(float4 a, float4 b) {
    return fmaf(a.x, b.x, fmaf(a.y, b.y, fmaf(a.z, b.z, a.w * b.w)));
}

// K1: M[b,h,q] = max_s dot(Q[bhq], K[bh,idx[q,s]]) - (1/L) * sum_s dot(...)
// FP32 ONLY (top-k ordering; fp16 noise permutes rows). 38-44 us across 3
// structural variants -> L2 gather-bandwidth ceiling. UNCHANGED.
__global__ __launch_bounds__(256) void k_msamp(const float* __restrict__ Q,
                                               const float* __restrict__ K,
                                               const int* __restrict__ idx,
                                               float* __restrict__ M) {
    int g  = blockIdx.x & 7;        // = b*2 + hh  (XCD id under %8 round-robin)
    int b  = g >> 1;
    int hh = g & 1;
    int t  = threadIdx.x;
    int wave = t >> 6;
    int lane = t & 63;
    int qp = lane >> 5;
    int hp = (lane >> 3) & 3;
    int c  = lane & 7;
    int h  = hh * 4 + hp;
    int q  = (blockIdx.x >> 3) * 8 + wave * 2 + qp;

    const float* qrow = Q + (size_t)((b * L + q) * H + h) * D + c * 8;
    float4 qa = *(const float4*)qrow;
    float4 qb = *(const float4*)(qrow + 4);

    int s1 = lane & 31;
    int v1 = idx[q * SK + s1];
    int s2 = 32 + s1; if (s2 > SK - 1) s2 = SK - 1;
    int v2 = idx[q * SK + s2];

    const float* kbase = K + (size_t)b * L * H * D + (size_t)h * D + c * 8;

    float vmax = -__builtin_inff();
    float vsum = 0.f;
#pragma unroll 8
    for (int s = 0; s < SK; ++s) {
        int kidx = (s < 32) ? __shfl(v1, qp * 32 + s, 64)
                            : __shfl(v2, qp * 32 + (s - 32), 64);
        const float* kp = kbase + (size_t)kidx * (H * D);
        float4 ka = *(const float4*)kp;
        float4 kb = *(const float4*)(kp + 4);
        float d8 = dot4(qa, ka) + dot4(qb, kb);
        d8 += __shfl_xor(d8, 1, 64);
        d8 += __shfl_xor(d8, 2, 64);
        d8 += __shfl_xor(d8, 4, 64);
        vmax = fmaxf(vmax, d8);
        vsum += d8;
    }
    if (c == 0) M[(size_t)(b * H + h) * L + q] = vmax - vsum * (1.0f / (float)L);
}

// K2: top-U per (b,h). Order: value desc, ties -> lowest index. UNCHANGED.
__global__ __launch_bounds__(256) void k_topk(const float* __restrict__ M,
                                              int* __restrict__ top) {
    __shared__ unsigned long long cand[L];
    __shared__ unsigned int bins[256];
    __shared__ unsigned int red[256];
    __shared__ int cnt2;

    int bh = blockIdx.x;
    int tid = threadIdx.x;
    const float* m = M + (size_t)bh * L;

    bins[tid] = 0;
    if (tid == 0) cnt2 = 0;

    const float4* m4 = (const float4*)(m + tid * 8);
    float4 fa = m4[0], fb = m4[1];
    float f8[8] = {fa.x, fa.y, fa.z, fa.w, fb.x, fb.y, fb.z, fb.w};
    unsigned int u8[8];
    unsigned int umin = 0xFFFFFFFFu, umax = 0u;
#pragma unroll
    for (int e = 0; e < 8; ++e) {
        unsigned int bits = __float_as_uint(f8[e]);
        unsigned int u = (bits & 0x80000000u) ? ~bits : (bits | 0x80000000u);
        u8[e] = u;
        umin = min(umin, u);
        umax = max(umax, u);
    }
    red[tid] = umin;
    __syncthreads();
    for (int s = 128; s; s >>= 1) {
        if (tid < s) red[tid] = min(red[tid], red[tid + s]);
        __syncthreads();
    }
    unsigned int kmin = red[0];
    __syncthreads();
    red[tid] = umax;
    __syncthreads();
    for (int s = 128; s; s >>= 1) {
        if (tid < s) red[tid] = max(red[tid], red[tid + s]);
        __syncthreads();
    }
    unsigned int kmax = red[0];
    __syncthreads();

    unsigned int range = kmax - kmin;
    if (range == 0u) {
        if (tid < U) top[bh * U + tid] = tid;
        return;
    }
    int hb = 31 - __clz(range);
    int shift = (hb > 7) ? (hb - 7) : 0;

#pragma unroll
    for (int e = 0; e < 8; ++e) {
        unsigned int bin = (u8[e] - kmin) >> shift;
        atomicAdd(&bins[bin], 1u);
    }
    __syncthreads();

    red[tid] = bins[tid];
    __syncthreads();
    for (int s = 1; s < 256; s <<= 1) {
        unsigned int add = (tid + s < 256) ? red[tid + s] : 0u;
        __syncthreads();
        red[tid] += add;
        __syncthreads();
    }
    int cnt = __syncthreads_count(red[tid] >= U);
    unsigned int t = (unsigned int)(cnt - 1);

#pragma unroll
    for (int e = 0; e < 8; ++e) {
        unsigned int u = u8[e];
        if (((u - kmin) >> shift) >= t) {
            int pos = atomicAdd(&cnt2, 1);
            int i = tid * 8 + e;
            cand[pos] = ((unsigned long long)u << 11) | (unsigned long long)(2047 - i);
        }
    }
    __syncthreads();
    int C = cnt2;

    for (int j = tid; j < C; j += 256) {
        unsigned long long kj = cand[j];
        int r = 0;
        for (int kk = 0; kk < C; ++kk) r += (cand[kk] > kj);
        if (r < U) top[bh * U + r] = 2047 - (int)(kj & 0x7FFull);
    }
}

// ---- Tail phases: regular launches, occupancy-first decomposition ----
// R2/R3 post-mortem: cooperative fusion costs ~55-85 us of launch/graph
// overhead (coop k_tail 80.7us but totals 212-228 vs 150.7 un-fused), and the
// ORIGINAL tail kernels were slow due to 8-waves/CU latency starvation, not
// launch gaps. So: regular launches, R3's verified phase bodies, grids of
// 512 blocks x 512 thr (2-4 blocks/CU -> 16-32 waves/CU, scheduler free to
// oversubscribe, which a 1-block/CU coop grid forbids).

// Phase A: E[bh,u,k] = exp(0.125*dot(Q[top[u]],K[k])), csum = per-64-col sums.
// fp32, no max-sub (|score| <~ 6 fp32-safe; normalization in phase C).
// Block = one (bh, 128-col chunk): thread owns ONE K column (16 float4) x 10 u.
__global__ __launch_bounds__(512, 4) void k_phA(const float* __restrict__ Q,
                                                const float* __restrict__ K,
                                                const int* __restrict__ top,
                                                float* __restrict__ T,
                                                float* __restrict__ csum) {
    __shared__ __align__(16) float4 sQ4[U * 16];   // 10 KB
    int tid = threadIdx.x;
    int bh = blockIdx.x >> 4;        // 32 bh
    int kc = blockIdx.x & 15;        // 16 chunks of 128 columns
    int b = bh >> 3, h = bh & (H - 1);

    for (int i = tid; i < U * 16; i += 512) {
        int u = i >> 4, c = i & 15;
        int qidx = top[bh * U + u];
        sQ4[i] = *((const float4*)(Q + (size_t)((b * L + qidx) * H + h) * D) + c);
    }

    int ugrp   = tid >> 7;           // 0..3 -> u in [10*ugrp, 10*ugrp+10)
    int colgrp = tid & 127;          // column within chunk
    int col = kc * 128 + colgrp;

    const float4* kr = (const float4*)(K + (size_t)((b * L + col) * H + h) * D);
    float4 kv[16];
#pragma unroll
    for (int i = 0; i < 16; ++i) kv[i] = kr[i];
    __syncthreads();

    float* Tb = T + (size_t)bh * U * L;
    int cs = 2 * kc + (colgrp >> 6); // 64-col sub-chunk id (wave-uniform)
#pragma unroll
    for (int uu = 0; uu < 10; ++uu) {
        int u = ugrp * 10 + uu;
        float s = 0.f;
#pragma unroll
        for (int i = 0; i < 16; ++i) s += dot4(sQ4[u * 16 + i], kv[i]);
        float e = __expf(s * 0.125f);
        Tb[(size_t)u * L + col] = e;   // wave writes 64 consecutive floats
        float c0 = e;
#pragma unroll
        for (int o = 1; o < 64; o <<= 1) c0 += __shfl_xor(c0, o, 64);
        if ((colgrp & 63) == 0) csum[((size_t)bh * U + u) * CSG + cs] = c0;
    }
}

// Phase B: block = one (bh, 128-j chunk): in-wave suffix scan of E (+ csum
// tail), then part[jc,bh,u,d] = sum_j Tsuf[u,j]*V[b,j,h,d]. 8 waves x 5 u.
__global__ __launch_bounds__(512, 4) void k_phB(const float* __restrict__ V,
                                                const float* __restrict__ T,
                                                const float* __restrict__ csum,
                                                float* __restrict__ part) {
    __shared__ __align__(16) float sT[U * JCL];    // 20 KB
    int tid = threadIdx.x;
    int bh = blockIdx.x >> 4;
    int jc = blockIdx.x & 15;
    int b = bh >> 3, h = bh & (H - 1);
    int w8   = tid >> 6;             // wave: u in [5*w8, 5*w8+5)
    int lane = tid & 63;

    int j2 = lane >> 4;
    int d4 = lane & 15;
    int jlane = lane & 31;

    const float* Eg = T + (size_t)bh * U * L + jc * JCL;
    for (int r = 0; r < 5; ++r) {
        int u = w8 * 5 + r;
        // tail = sum of csum sub-chunks beyond this 128-j chunk
        float cv = csum[((size_t)bh * U + u) * CSG + jlane];
        float tv = (jlane > 2 * jc + 1) ? cv : 0.f;
        tv += __shfl_xor(tv, 1, 64);
        tv += __shfl_xor(tv, 2, 64);
        tv += __shfl_xor(tv, 4, 64);
        tv += __shfl_xor(tv, 8, 64);
        tv += __shfl_xor(tv, 16, 64);
        float el = Eg[(size_t)u * L + lane];
        float eh = Eg[(size_t)u * L + 64 + lane];
        float sh = eh;
#pragma unroll
        for (int s = 1; s < 64; s <<= 1) {
            float o = __shfl_down(sh, s, 64);
            sh += (lane + s < 64) ? o : 0.f;
        }
        float th = __shfl(sh, 0, 64);   // total of hi half
        float sl = el;
#pragma unroll
        for (int s = 1; s < 64; s <<= 1) {
            float o = __shfl_down(sl, s, 64);
            sl += (lane + s < 64) ? o : 0.f;
        }
        sT[u * JCL + lane]      = sl + th + tv;
        sT[u * JCL + 64 + lane] = sh + tv;
    }
    __syncthreads();

    float4 acc[5];
#pragma unroll
    for (int uu = 0; uu < 5; ++uu) acc[uu] = make_float4(0.f, 0.f, 0.f, 0.f);

    const float* Vb = V + (size_t)(b * L) * (H * D) + (size_t)h * D + d4 * 4;
#pragma unroll 4
    for (int it = 0; it < JCL / 4; ++it) {
        int j = it * 4 + j2;
        float4 v4 = *(const float4*)(Vb + (size_t)(jc * JCL + j) * (H * D));
#pragma unroll
        for (int uu = 0; uu < 5; ++uu) {
            float tj = sT[(w8 * 5 + uu) * JCL + j];   // broadcast LDS read
            acc[uu].x = fmaf(tj, v4.x, acc[uu].x);
            acc[uu].y = fmaf(tj, v4.y, acc[uu].y);
            acc[uu].z = fmaf(tj, v4.z, acc[uu].z);
            acc[uu].w = fmaf(tj, v4.w, acc[uu].w);
        }
    }

    float* po = part + ((size_t)jc * (B * H) + bh) * (U * D);
#pragma unroll
    for (int uu = 0; uu < 5; ++uu) {
        float4 a = acc[uu];
        a.x += __shfl_xor(a.x, 16, 64); a.y += __shfl_xor(a.y, 16, 64);
        a.z += __shfl_xor(a.z, 16, 64); a.w += __shfl_xor(a.w, 16, 64);
        a.x += __shfl_xor(a.x, 32, 64); a.y += __shfl_xor(a.y, 32, 64);
        a.z += __shfl_xor(a.z, 32, 64); a.w += __shfl_xor(a.w, 32, 64);
        if (j2 == 0) *(float4*)(po + (w8 * 5 + uu) * D + d4 * 4) = a;
    }
}

// Phase C: final reduce over JC j-chunks + softmax normalization (denominator
// from csum inline; block covers 4 u-rows of one bh). 320 blocks x 256 thr.
__global__ __launch_bounds__(256) void k_red(const float* __restrict__ part,
                                             const float* __restrict__ csum,
                                             float* __restrict__ out) {
    __shared__ float sden[4];
    int o = blockIdx.x * 256 + threadIdx.x;
    int bh = o / (U * D);
    int rest = o - bh * (U * D);
    int u = rest >> 6;
    int tid = threadIdx.x;
    int ubase = ((blockIdx.x * 256) % (U * D)) >> 6;

    if (tid < 128) {
        int ul = tid >> 5, j = tid & 31;
        float v = csum[((size_t)bh * U + ubase + ul) * CSG + j];
        v += __shfl_xor(v, 1, 64);
        v += __shfl_xor(v, 2, 64);
        v += __shfl_xor(v, 4, 64);
        v += __shfl_xor(v, 8, 64);
        v += __shfl_xor(v, 16, 64);
        if (j == 0) sden[ul] = v;
    }
    __syncthreads();

    float s = 0.f;
#pragma unroll
    for (int jc = 0; jc < JC; ++jc)
        s += part[(size_t)(jc * (B * H) + bh) * (U * D) + rest];
    out[o] = s / sden[u - ubase];
}

extern "C" void kernel_launch(void* const* d_in, const int* in_sizes, int n_in,
                              void* d_out, int out_size, void* d_ws, size_t ws_size,
                              hipStream_t stream) {
    const float* Q  = (const float*)d_in[0];
    const float* K  = (const float*)d_in[1];
    const float* V  = (const float*)d_in[2];
    const int* idx  = (const int*)d_in[3];
    float* out = (float*)d_out;

    float* M    = (float*)((char*)d_ws + OFF_M);
    int*   top  = (int*)  ((char*)d_ws + OFF_TOP);
    float* T    = (float*)((char*)d_ws + OFF_T);
    float* part = (float*)((char*)d_ws + OFF_PART);
    float* csum = (float*)((char*)d_ws + OFF_CSUM);

    k_msamp<<<(L / 8) * 8, 256, 0, stream>>>(Q, K, idx, M);
    k_topk<<<B * H, 256, 0, stream>>>(M, top);
    k_phA<<<B * H * 16, 512, 0, stream>>>(Q, K, top, T, csum);
    k_phB<<<B * H * 16, 512, 0, stream>>>(V, T, csum, part);
    k_red<<<(B * H * U * D) / 256, 256, 0, stream>>>(part, csum, out);
}

// Round 5
// 140.631 us; speedup vs baseline: 1.6239x; 1.0239x over previous
//
#include <hip/hip_runtime.h>
#include <math.h>

#define B 4
#define L 2048
#define H 8
#define D 64
#define SK 40
#define U 40
#define JC 16          // j-chunks in tail (128 j per chunk)
#define JCL (L / JC)   // 128
#define CSG 32         // csum granularity: 32 sub-chunks of 64 columns

// ws layout (bytes) — T (E matrix) eliminated in R5: E lives in LDS of the
// fused k_phAB. part carries within-chunk-suffix context only; the cross-chunk
// tail is reconstructed in k_red from csum x Vsum (u-independent V chunk sums).
#define OFF_M     0                  // B*H*L floats = 262144 B
#define OFF_TOP   262144             // B*H*U ints  = 5120 B
#define OFF_PART  270336             // JC*B*H*U*D floats = 5242880 B
#define OFF_CSUM  5513216            // B*H*U*CSG floats = 163840 B
#define OFF_VSUM  5677056            // B*H*JC*D floats = 131072 B (end ~5.8 MB)

__device__ __forceinline__ float dot4(float4 a, float4 b) {
    return fmaf(a.x, b.x, fmaf(a.y, b.y, fmaf(a.z, b.z, a.w * b.w)));
}

// K1: M[b,h,q] = max_s dot(Q[bhq], K[bh,idx[q,s]]) - (1/L) * sum_s dot(...)
// FP32 ONLY (top-k ordering; fp16 noise permutes rows). 38-44 us across 3
// structural variants -> L2 gather-bandwidth ceiling (671 MB of 1 KB bursts;
// XCD-pinned 2.1 MB working set). UNCHANGED. Next candidate if needed:
// bucket (q,s) by K-row tile + LDS staging (est. 671 -> ~270 MB).
__global__ __launch_bounds__(256) void k_msamp(const float* __restrict__ Q,
                                               const float* __restrict__ K,
                                               const int* __restrict__ idx,
                                               float* __restrict__ M) {
    int g  = blockIdx.x & 7;        // = b*2 + hh  (XCD id under %8 round-robin)
    int b  = g >> 1;
    int hh = g & 1;
    int t  = threadIdx.x;
    int wave = t >> 6;
    int lane = t & 63;
    int qp = lane >> 5;
    int hp = (lane >> 3) & 3;
    int c  = lane & 7;
    int h  = hh * 4 + hp;
    int q  = (blockIdx.x >> 3) * 8 + wave * 2 + qp;

    const float* qrow = Q + (size_t)((b * L + q) * H + h) * D + c * 8;
    float4 qa = *(const float4*)qrow;
    float4 qb = *(const float4*)(qrow + 4);

    int s1 = lane & 31;
    int v1 = idx[q * SK + s1];
    int s2 = 32 + s1; if (s2 > SK - 1) s2 = SK - 1;
    int v2 = idx[q * SK + s2];

    const float* kbase = K + (size_t)b * L * H * D + (size_t)h * D + c * 8;

    float vmax = -__builtin_inff();
    float vsum = 0.f;
#pragma unroll 8
    for (int s = 0; s < SK; ++s) {
        int kidx = (s < 32) ? __shfl(v1, qp * 32 + s, 64)
                            : __shfl(v2, qp * 32 + (s - 32), 64);
        const float* kp = kbase + (size_t)kidx * (H * D);
        float4 ka = *(const float4*)kp;
        float4 kb = *(const float4*)(kp + 4);
        float d8 = dot4(qa, ka) + dot4(qb, kb);
        d8 += __shfl_xor(d8, 1, 64);
        d8 += __shfl_xor(d8, 2, 64);
        d8 += __shfl_xor(d8, 4, 64);
        vmax = fmaxf(vmax, d8);
        vsum += d8;
    }
    if (c == 0) M[(size_t)(b * H + h) * L + q] = vmax - vsum * (1.0f / (float)L);
}

// K2: top-U per (b,h). Order: value desc, ties -> lowest index. UNCHANGED.
__global__ __launch_bounds__(256) void k_topk(const float* __restrict__ M,
                                              int* __restrict__ top) {
    __shared__ unsigned long long cand[L];
    __shared__ unsigned int bins[256];
    __shared__ unsigned int red[256];
    __shared__ int cnt2;

    int bh = blockIdx.x;
    int tid = threadIdx.x;
    const float* m = M + (size_t)bh * L;

    bins[tid] = 0;
    if (tid == 0) cnt2 = 0;

    const float4* m4 = (const float4*)(m + tid * 8);
    float4 fa = m4[0], fb = m4[1];
    float f8[8] = {fa.x, fa.y, fa.z, fa.w, fb.x, fb.y, fb.z, fb.w};
    unsigned int u8[8];
    unsigned int umin = 0xFFFFFFFFu, umax = 0u;
#pragma unroll
    for (int e = 0; e < 8; ++e) {
        unsigned int bits = __float_as_uint(f8[e]);
        unsigned int u = (bits & 0x80000000u) ? ~bits : (bits | 0x80000000u);
        u8[e] = u;
        umin = min(umin, u);
        umax = max(umax, u);
    }
    red[tid] = umin;
    __syncthreads();
    for (int s = 128; s; s >>= 1) {
        if (tid < s) red[tid] = min(red[tid], red[tid + s]);
        __syncthreads();
    }
    unsigned int kmin = red[0];
    __syncthreads();
    red[tid] = umax;
    __syncthreads();
    for (int s = 128; s; s >>= 1) {
        if (tid < s) red[tid] = max(red[tid], red[tid + s]);
        __syncthreads();
    }
    unsigned int kmax = red[0];
    __syncthreads();

    unsigned int range = kmax - kmin;
    if (range == 0u) {
        if (tid < U) top[bh * U + tid] = tid;
        return;
    }
    int hb = 31 - __clz(range);
    int shift = (hb > 7) ? (hb - 7) : 0;

#pragma unroll
    for (int e = 0; e < 8; ++e) {
        unsigned int bin = (u8[e] - kmin) >> shift;
        atomicAdd(&bins[bin], 1u);
    }
    __syncthreads();

    red[tid] = bins[tid];
    __syncthreads();
    for (int s = 1; s < 256; s <<= 1) {
        unsigned int add = (tid + s < 256) ? red[tid + s] : 0u;
        __syncthreads();
        red[tid] += add;
        __syncthreads();
    }
    int cnt = __syncthreads_count(red[tid] >= U);
    unsigned int t = (unsigned int)(cnt - 1);

#pragma unroll
    for (int e = 0; e < 8; ++e) {
        unsigned int u = u8[e];
        if (((u - kmin) >> shift) >= t) {
            int pos = atomicAdd(&cnt2, 1);
            int i = tid * 8 + e;
            cand[pos] = ((unsigned long long)u << 11) | (unsigned long long)(2047 - i);
        }
    }
    __syncthreads();
    int C = cnt2;

    for (int j = tid; j < C; j += 256) {
        unsigned long long kj = cand[j];
        int r = 0;
        for (int kk = 0; kk < C; ++kk) r += (cand[kk] > kj);
        if (r < U) top[bh * U + r] = 2047 - (int)(kj & 0x7FFull);
    }
}

// K3 (fused A+B): block = one (bh, 128-col chunk jc), 512 thr, 8 waves.
//   Step 1: Q-top rows -> LDS (10 KB).
//   Step 2 (== old phA): thread owns one K column (16 float4 regs) x 10 u;
//     E = exp(0.125*dot) written to LDS sE[u][128] (NOT global — the 21 MB
//     E round-trip of R4 is eliminated); per-64-col csum -> global (k_red
//     needs it for denominators + cross-chunk tails).
//   Step 3 (== old phB scan, minus tv): per-wave within-chunk inclusive
//     suffix of its 5 sE rows, in place. No cross-wave LDS use after sync.
//   Step 4 (== old phB PV): part[jc,bh,u,d] = sum_j sufE[u,j]*V[b,j,h,d];
//     wave 0 additionally emits Vsum[bh,jc,d] = sum_j V[j,d] (u-independent)
//     so k_red can add  sum_jc tailw[u,jc]*Vsum[jc,d]  — algebraically equal
//     to the old in-chunk tv term (tv * sum_j V[j]).
// fp32 throughout; no max-sub (|score| <~ 6 fp32-safe).
__global__ __launch_bounds__(512, 4) void k_phAB(const float* __restrict__ Q,
                                                 const float* __restrict__ K,
                                                 const int* __restrict__ top,
                                                 const float* __restrict__ V,
                                                 float* __restrict__ part,
                                                 float* __restrict__ csum,
                                                 float* __restrict__ vsum) {
    __shared__ __align__(16) float4 sQ4[U * 16];   // 10 KB
    __shared__ __align__(16) float sE[U * JCL];    // 20 KB
    int tid = threadIdx.x;
    int bh = blockIdx.x >> 4;        // 32 bh
    int jc = blockIdx.x & 15;        // 16 chunks of 128 columns (= j-chunks)
    int b = bh >> 3, h = bh & (H - 1);

    // Step 1
    for (int i = tid; i < U * 16; i += 512) {
        int u = i >> 4, c = i & 15;
        int qidx = top[bh * U + u];
        sQ4[i] = *((const float4*)(Q + (size_t)((b * L + qidx) * H + h) * D) + c);
    }

    // Step 2: E into LDS + csum
    int ugrp   = tid >> 7;           // 0..3 -> u in [10*ugrp, 10*ugrp+10)
    int colgrp = tid & 127;          // column within chunk
    int col = jc * 128 + colgrp;

    const float4* kr = (const float4*)(K + (size_t)((b * L + col) * H + h) * D);
    float4 kv[16];
#pragma unroll
    for (int i = 0; i < 16; ++i) kv[i] = kr[i];
    __syncthreads();

    int cs = 2 * jc + (colgrp >> 6); // 64-col sub-chunk id (wave-uniform)
#pragma unroll
    for (int uu = 0; uu < 10; ++uu) {
        int u = ugrp * 10 + uu;
        float s = 0.f;
#pragma unroll
        for (int i = 0; i < 16; ++i) s += dot4(sQ4[u * 16 + i], kv[i]);
        float e = __expf(s * 0.125f);
        sE[u * JCL + colgrp] = e;
        float c0 = e;
#pragma unroll
        for (int o = 1; o < 64; o <<= 1) c0 += __shfl_xor(c0, o, 64);
        if ((colgrp & 63) == 0) csum[((size_t)bh * U + u) * CSG + cs] = c0;
    }
    __syncthreads();

    // Step 3: within-chunk inclusive suffix, in place (each wave owns its 5 u
    // rows exclusively from here on — no further cross-wave LDS sharing).
    int w8   = tid >> 6;             // wave: u in [5*w8, 5*w8+5)
    int lane = tid & 63;
    for (int r = 0; r < 5; ++r) {
        int u = w8 * 5 + r;
        float el = sE[u * JCL + lane];
        float eh = sE[u * JCL + 64 + lane];
        float sh = eh;
#pragma unroll
        for (int s = 1; s < 64; s <<= 1) {
            float o = __shfl_down(sh, s, 64);
            sh += (lane + s < 64) ? o : 0.f;
        }
        float th = __shfl(sh, 0, 64);   // total of hi half
        float sl = el;
#pragma unroll
        for (int s = 1; s < 64; s <<= 1) {
            float o = __shfl_down(sl, s, 64);
            sl += (lane + s < 64) ? o : 0.f;
        }
        sE[u * JCL + lane]      = sl + th;
        sE[u * JCL + 64 + lane] = sh;
    }

    // Step 4: PV + Vsum
    int j2 = lane >> 4;
    int d4 = lane & 15;

    float4 acc[5];
#pragma unroll
    for (int uu = 0; uu < 5; ++uu) acc[uu] = make_float4(0.f, 0.f, 0.f, 0.f);
    float4 vs = make_float4(0.f, 0.f, 0.f, 0.f);

    const float* Vb = V + (size_t)(b * L) * (H * D) + (size_t)h * D + d4 * 4;
#pragma unroll 4
    for (int it = 0; it < JCL / 4; ++it) {
        int j = it * 4 + j2;
        float4 v4 = *(const float4*)(Vb + (size_t)(jc * JCL + j) * (H * D));
        vs.x += v4.x; vs.y += v4.y; vs.z += v4.z; vs.w += v4.w;
#pragma unroll
        for (int uu = 0; uu < 5; ++uu) {
            float tj = sE[(w8 * 5 + uu) * JCL + j];   // broadcast LDS read
            acc[uu].x = fmaf(tj, v4.x, acc[uu].x);
            acc[uu].y = fmaf(tj, v4.y, acc[uu].y);
            acc[uu].z = fmaf(tj, v4.z, acc[uu].z);
            acc[uu].w = fmaf(tj, v4.w, acc[uu].w);
        }
    }

    float* po = part + ((size_t)jc * (B * H) + bh) * (U * D);
#pragma unroll
    for (int uu = 0; uu < 5; ++uu) {
        float4 a = acc[uu];
        a.x += __shfl_xor(a.x, 16, 64); a.y += __shfl_xor(a.y, 16, 64);
        a.z += __shfl_xor(a.z, 16, 64); a.w += __shfl_xor(a.w, 16, 64);
        a.x += __shfl_xor(a.x, 32, 64); a.y += __shfl_xor(a.y, 32, 64);
        a.z += __shfl_xor(a.z, 32, 64); a.w += __shfl_xor(a.w, 32, 64);
        if (j2 == 0) *(float4*)(po + (w8 * 5 + uu) * D + d4 * 4) = a;
    }
    if (w8 == 0) {
        vs.x += __shfl_xor(vs.x, 16, 64); vs.y += __shfl_xor(vs.y, 16, 64);
        vs.z += __shfl_xor(vs.z, 16, 64); vs.w += __shfl_xor(vs.w, 16, 64);
        vs.x += __shfl_xor(vs.x, 32, 64); vs.y += __shfl_xor(vs.y, 32, 64);
        vs.z += __shfl_xor(vs.z, 32, 64); vs.w += __shfl_xor(vs.w, 32, 64);
        if (j2 == 0)
            *(float4*)(vsum + ((size_t)bh * JC + jc) * D + d4 * 4) = vs;
    }
}

// K4: final reduce: out[u,d] = (sum_jc part + sum_jc tailw[u,jc]*Vsum[jc,d])
// / den[u]. tailw/den from a 32-wide suffix scan of csum. Block = 4 u-rows
// of one bh (10 blocks per bh, 320 total).
__global__ __launch_bounds__(256) void k_red(const float* __restrict__ part,
                                             const float* __restrict__ csum,
                                             const float* __restrict__ vsum,
                                             float* __restrict__ out) {
    __shared__ float sden[4];
    __shared__ float stw[4][JC];
    int o = blockIdx.x * 256 + threadIdx.x;
    int bh = o / (U * D);
    int rest = o - bh * (U * D);
    int u = rest >> 6;
    int d = rest & 63;
    int tid = threadIdx.x;
    int ubase = ((blockIdx.x * 256) % (U * D)) >> 6;

    if (tid < 128) {
        int ul = tid >> 5, cs = tid & 31;
        float v = csum[((size_t)bh * U + ubase + ul) * CSG + cs];
        // inclusive suffix within each 32-lane group
#pragma unroll
        for (int s = 1; s < 32; s <<= 1) {
            float ov = __shfl_down(v, s, 64);
            v += (cs + s < 32) ? ov : 0.f;
        }
        if (cs == 0) { sden[ul] = v; stw[ul][JC - 1] = 0.f; }
        if ((cs & 1) == 0 && cs >= 2) stw[ul][(cs >> 1) - 1] = v;
    }
    __syncthreads();

    int ul = u - ubase;
    float s = 0.f;
#pragma unroll
    for (int jc = 0; jc < JC; ++jc)
        s += part[(size_t)(jc * (B * H) + bh) * (U * D) + rest];
#pragma unroll
    for (int jc = 0; jc < JC; ++jc)
        s = fmaf(stw[ul][jc], vsum[((size_t)bh * JC + jc) * D + d], s);
    out[o] = s / sden[ul];
}

extern "C" void kernel_launch(void* const* d_in, const int* in_sizes, int n_in,
                              void* d_out, int out_size, void* d_ws, size_t ws_size,
                              hipStream_t stream) {
    const float* Q  = (const float*)d_in[0];
    const float* K  = (const float*)d_in[1];
    const float* V  = (const float*)d_in[2];
    const int* idx  = (const int*)d_in[3];
    float* out = (float*)d_out;

    float* M    = (float*)((char*)d_ws + OFF_M);
    int*   top  = (int*)  ((char*)d_ws + OFF_TOP);
    float* part = (float*)((char*)d_ws + OFF_PART);
    float* csum = (float*)((char*)d_ws + OFF_CSUM);
    float* vsum = (float*)((char*)d_ws + OFF_VSUM);

    k_msamp<<<(L / 8) * 8, 256, 0, stream>>>(Q, K, idx, M);
    k_topk<<<B * H, 256, 0, stream>>>(M, top);
    k_phAB<<<B * H * JC, 512, 0, stream>>>(Q, K, top, V, part, csum, vsum);
    k_red<<<(B * H * U * D) / 256, 256, 0, stream>>>(part, csum, vsum, out);
}